// Round 2
// baseline (277.973 us; speedup 1.0000x reference)
//
#include <hip/hip_runtime.h>

#define ROWS 16384   // B*N = 4*4096
#define DIM 64
#define NCODES 8192
#define KT 256       // codes per k-tile block

// Map float to order-preserving uint, pack with (0xFFFF - idx) so that
// u64 max = (max score, then lowest index) == jnp.argmax first-max semantics.
__device__ __forceinline__ unsigned long long pack_score(float s, int idx) {
  unsigned u = __float_as_uint(s);
  u ^= (unsigned)((int)u >> 31) | 0x80000000u;
  return ((unsigned long long)u << 32) | (unsigned)(0xFFFF - idx);
}

__global__ void vq_enorm(const float* __restrict__ embed, float* __restrict__ enh) {
  int k = blockIdx.x * 256 + threadIdx.x;
  const float4* e4 = (const float4*)(embed + (size_t)k * DIM);
  float a = 0.f, b = 0.f, c = 0.f, d = 0.f;
#pragma unroll
  for (int i = 0; i < DIM / 4; ++i) {
    float4 v = e4[i];
    a = fmaf(v.x, v.x, a);
    b = fmaf(v.y, v.y, b);
    c = fmaf(v.z, v.z, c);
    d = fmaf(v.w, v.w, d);
  }
  enh[k] = 0.5f * ((a + b) + (c + d));  // ||e||^2 / 2
}

// One row per thread, x register-resident (64 VGPR -> 4 waves/SIMD tier).
// embed row address is wave-uniform -> scalar s_load through constant cache;
// e rides the SGPR operand port of v_fma (1 SGPR src allowed), x is the VGPR src.
__global__ __launch_bounds__(256, 4) void vq_score(
    const float* __restrict__ x, const float* __restrict__ embed,
    const float* __restrict__ enh, unsigned long long* __restrict__ best) {
  const int row = blockIdx.x * 256 + threadIdx.x;
  const int c0 = blockIdx.y * KT;

  float4 xa[16];
  const float4* xg = (const float4*)(x + (size_t)row * DIM);
#pragma unroll
  for (int i = 0; i < 16; ++i) xa[i] = xg[i];

  float bs = -3.4e38f;
  int bc = 0;
#pragma unroll 2
  for (int c = c0; c < c0 + KT; ++c) {
    const float4* e4 = (const float4*)(embed + (size_t)c * DIM);
    float a0 = 0.f, a1 = 0.f, a2 = 0.f, a3 = 0.f;
#pragma unroll
    for (int i = 0; i < 16; ++i) {
      float4 ev = e4[i];
      a0 = fmaf(xa[i].x, ev.x, a0);
      a1 = fmaf(xa[i].y, ev.y, a1);
      a2 = fmaf(xa[i].z, ev.z, a2);
      a3 = fmaf(xa[i].w, ev.w, a3);
    }
    float s = ((a0 + a1) + (a2 + a3)) - enh[c];  // x.e - ||e||^2/2, same argmax as ref
    if (s > bs) { bs = s; bc = c; }              // strict > keeps first max within tile
  }
  atomicMax(&best[row], pack_score(bs, bc));
}

__global__ void vq_finalize(const unsigned long long* __restrict__ best,
                            const float* __restrict__ embed,
                            const float* __restrict__ node_mask,
                            float* __restrict__ quant,
                            float* __restrict__ out_idx,
                            float* __restrict__ counts) {
  int gid = blockIdx.x * 256 + threadIdx.x;  // ROWS*64 threads
  int row = gid >> 6, d = gid & 63;
  unsigned long long p = best[row];
  int idx = 0xFFFF - (int)(p & 0xFFFFull);
  quant[gid] = embed[(size_t)idx * DIM + d];
  if (d == 0) {
    out_idx[row] = (float)idx;
    atomicAdd(&counts[idx], node_mask[row]);  // exact: addends are 1.0f
  }
}

__global__ void vq_perplexity(const float* __restrict__ counts, float* __restrict__ out) {
  int tid = threadIdx.x;
  float acc = 0.f;
  for (int k = tid; k < NCODES; k += 256) {
    float p = counts[k] * (1.0f / (float)ROWS);
    acc += p * logf(p + 1e-10f);
  }
#pragma unroll
  for (int off = 32; off > 0; off >>= 1) acc += __shfl_down(acc, off);
  __shared__ float red[4];
  if ((tid & 63) == 0) red[tid >> 6] = acc;
  __syncthreads();
  if (tid == 0) out[0] = expf(-((red[0] + red[1]) + (red[2] + red[3])));
}

extern "C" void kernel_launch(void* const* d_in, const int* in_sizes, int n_in,
                              void* d_out, int out_size, void* d_ws, size_t ws_size,
                              hipStream_t stream) {
  const float* x = (const float*)d_in[0];
  const float* node_mask = (const float*)d_in[1];
  const float* embed = (const float*)d_in[2];

  float* out = (float*)d_out;
  float* quant = out;                        // [ROWS*DIM]
  float* out_idx = out + (size_t)ROWS * DIM; // [ROWS] (indices as float)
  float* out_ppl = out_idx + ROWS;           // [1]

  unsigned long long* best = (unsigned long long*)d_ws;       // 131072 B
  float* counts = (float*)((char*)d_ws + ROWS * 8);           // 32768 B
  float* enh = (float*)((char*)d_ws + ROWS * 8 + NCODES * 4); // 32768 B

  // zero best (packed-min) + counts; enh fully overwritten by vq_enorm
  hipMemsetAsync(d_ws, 0, ROWS * 8 + NCODES * 4, stream);
  vq_enorm<<<NCODES / 256, 256, 0, stream>>>(embed, enh);
  vq_score<<<dim3(ROWS / 256, NCODES / KT), 256, 0, stream>>>(x, embed, enh, best);
  vq_finalize<<<ROWS * DIM / 256, 256, 0, stream>>>(best, embed, node_mask, quant, out_idx, counts);
  vq_perplexity<<<1, 256, 0, stream>>>(counts, out_ppl);
}

// Round 3
// 132.035 us; speedup vs baseline: 2.1053x; 2.1053x over previous
//
#include <hip/hip_runtime.h>

typedef __attribute__((ext_vector_type(8))) short short8;
typedef __attribute__((ext_vector_type(4))) float f32x4;

#define ROWS 16384   // B*N
#define DIM 64
#define NCODES 8192
#define MARGIN 0.008f
#define KT_FB 256

// ws layout (bytes)
#define WS_BEST   0            // 16384 * 8
#define WS_COUNTS 131072       // 8192 * 4
#define WS_ENH    163840       // 8192 * 4
#define WS_ESWZ   196608       // 8192*64*2 terms * 2B = 2097152
#define WS_NEED   2293760

__device__ __forceinline__ unsigned long long pack_score(float s, int idx) {
  unsigned u = __float_as_uint(s);
  u ^= (unsigned)((int)u >> 31) | 0x80000000u;
  return ((unsigned long long)u << 32) | (unsigned)(0xFFFF - idx);
}
__device__ __forceinline__ unsigned short bf16hi(float f) {
  unsigned u = __float_as_uint(f);
  return (unsigned short)((u + 0x7FFFu + ((u >> 16) & 1u)) >> 16);
}

__global__ void vq_enorm(const float* __restrict__ embed, float* __restrict__ enh) {
  int k = blockIdx.x * 256 + threadIdx.x;
  const float4* e4 = (const float4*)(embed + (size_t)k * DIM);
  float a = 0.f, b = 0.f, c = 0.f, d = 0.f;
#pragma unroll
  for (int i = 0; i < DIM / 4; ++i) {
    float4 v = e4[i];
    a = fmaf(v.x, v.x, a); b = fmaf(v.y, v.y, b);
    c = fmaf(v.z, v.z, c); d = fmaf(v.w, v.w, d);
  }
  enh[k] = 0.5f * ((a + b) + (c + d));
}

// Pre-swizzle embed into MFMA B-fragment order, split hi/lo bf16.
// frag element (ct,kc,term,l,j) = bf16part(embed[ct*16+(l&15)][kc*32+(l>>4)*8+j])
__global__ void vq_prep_e(const float* __restrict__ embed, short* __restrict__ eswz) {
  int u = blockIdx.x * 256 + threadIdx.x;  // 65536 = 512ct * 2kc * 64l
  int l = u & 63, kc = (u >> 6) & 1, ct = u >> 7;
  int code = ct * 16 + (l & 15);
  int kb = kc * 32 + (l >> 4) * 8;
  const float* er = embed + (size_t)code * DIM + kb;
  short8 h8, l8;
#pragma unroll
  for (int j = 0; j < 8; ++j) {
    float v = er[j];
    unsigned short h = bf16hi(v);
    float r = v - __uint_as_float((unsigned)h << 16);
    h8[j] = (short)h;
    l8[j] = (short)bf16hi(r);
  }
  short8* dst = (short8*)eswz;
  size_t frag = (size_t)(ct * 2 + kc) * 2;
  dst[(frag + 0) * 64 + l] = h8;
  dst[(frag + 1) * 64 + l] = l8;
}

// Screen: wave = 64 rows x 1024 codes. Split-bf16 MFMA (hi*hi + hi*lo + lo*hi),
// per-lane running argmax, cross-lane max, margin-gated exact fp32 rescore,
// packed u64 atomicMax combine across the 8 code-split blocks.
__global__ __launch_bounds__(256, 2) void vq_screen(
    const float* __restrict__ x, const float* __restrict__ embed,
    const short* __restrict__ eswz, const float* __restrict__ enh,
    unsigned long long* __restrict__ best) {
  const int l = threadIdx.x & 63, wid = threadIdx.x >> 6;
  const int cl = l & 15, grp = l >> 4;
  const int row0 = blockIdx.x * 256 + wid * 64;
  const int ct0 = blockIdx.y * 64;

  // A fragments: x rows -> hi/lo bf16, built in-register (one-time).
  short8 ahi[4][2], alo[4][2];
#pragma unroll
  for (int s = 0; s < 4; ++s) {
    const float* xr = x + (size_t)(row0 + s * 16 + cl) * DIM;
#pragma unroll
    for (int kc = 0; kc < 2; ++kc) {
      const int kb = kc * 32 + grp * 8;
#pragma unroll
      for (int j = 0; j < 8; ++j) {
        float v = xr[kb + j];
        unsigned short h = bf16hi(v);
        float r = v - __uint_as_float((unsigned)h << 16);
        ahi[s][kc][j] = (short)h;
        alo[s][kc][j] = (short)bf16hi(r);
      }
    }
  }

  const short8* eb = (const short8*)eswz;
  float bsc[4][4];
  int bidx[4][4];
#pragma unroll
  for (int s = 0; s < 4; ++s)
#pragma unroll
    for (int j = 0; j < 4; ++j) { bsc[s][j] = -3.4e38f; bidx[s][j] = 0; }

  short8 bh0, bl0, bh1, bl1;
  float eh;
  {
    size_t f0 = (size_t)(ct0 * 2 + 0) * 128, f1 = (size_t)(ct0 * 2 + 1) * 128;
    bh0 = eb[f0 + l]; bl0 = eb[f0 + 64 + l];
    bh1 = eb[f1 + l]; bl1 = eb[f1 + 64 + l];
    eh = enh[ct0 * 16 + cl];
  }

  for (int ct = ct0; ct < ct0 + 64; ++ct) {
    // prefetch next tile's B fragments (L2-resident)
    int ctn = (ct + 1 < ct0 + 64) ? ct + 1 : ct;
    size_t fn0 = (size_t)(ctn * 2 + 0) * 128, fn1 = (size_t)(ctn * 2 + 1) * 128;
    short8 nh0 = eb[fn0 + l], nl0 = eb[fn0 + 64 + l];
    short8 nh1 = eb[fn1 + l], nl1 = eb[fn1 + 64 + l];
    float ehx = enh[ctn * 16 + cl];

    f32x4 z = {0.f, 0.f, 0.f, 0.f};
    f32x4 acc0 = z, acc1 = z, acc2 = z, acc3 = z;
    // k-chunk 0
    acc0 = __builtin_amdgcn_mfma_f32_16x16x32_bf16(ahi[0][0], bh0, acc0, 0, 0, 0);
    acc1 = __builtin_amdgcn_mfma_f32_16x16x32_bf16(ahi[1][0], bh0, acc1, 0, 0, 0);
    acc2 = __builtin_amdgcn_mfma_f32_16x16x32_bf16(ahi[2][0], bh0, acc2, 0, 0, 0);
    acc3 = __builtin_amdgcn_mfma_f32_16x16x32_bf16(ahi[3][0], bh0, acc3, 0, 0, 0);
    acc0 = __builtin_amdgcn_mfma_f32_16x16x32_bf16(alo[0][0], bh0, acc0, 0, 0, 0);
    acc1 = __builtin_amdgcn_mfma_f32_16x16x32_bf16(alo[1][0], bh0, acc1, 0, 0, 0);
    acc2 = __builtin_amdgcn_mfma_f32_16x16x32_bf16(alo[2][0], bh0, acc2, 0, 0, 0);
    acc3 = __builtin_amdgcn_mfma_f32_16x16x32_bf16(alo[3][0], bh0, acc3, 0, 0, 0);
    acc0 = __builtin_amdgcn_mfma_f32_16x16x32_bf16(ahi[0][0], bl0, acc0, 0, 0, 0);
    acc1 = __builtin_amdgcn_mfma_f32_16x16x32_bf16(ahi[1][0], bl0, acc1, 0, 0, 0);
    acc2 = __builtin_amdgcn_mfma_f32_16x16x32_bf16(ahi[2][0], bl0, acc2, 0, 0, 0);
    acc3 = __builtin_amdgcn_mfma_f32_16x16x32_bf16(ahi[3][0], bl0, acc3, 0, 0, 0);
    // k-chunk 1
    acc0 = __builtin_amdgcn_mfma_f32_16x16x32_bf16(ahi[0][1], bh1, acc0, 0, 0, 0);
    acc1 = __builtin_amdgcn_mfma_f32_16x16x32_bf16(ahi[1][1], bh1, acc1, 0, 0, 0);
    acc2 = __builtin_amdgcn_mfma_f32_16x16x32_bf16(ahi[2][1], bh1, acc2, 0, 0, 0);
    acc3 = __builtin_amdgcn_mfma_f32_16x16x32_bf16(ahi[3][1], bh1, acc3, 0, 0, 0);
    acc0 = __builtin_amdgcn_mfma_f32_16x16x32_bf16(alo[0][1], bh1, acc0, 0, 0, 0);
    acc1 = __builtin_amdgcn_mfma_f32_16x16x32_bf16(alo[1][1], bh1, acc1, 0, 0, 0);
    acc2 = __builtin_amdgcn_mfma_f32_16x16x32_bf16(alo[2][1], bh1, acc2, 0, 0, 0);
    acc3 = __builtin_amdgcn_mfma_f32_16x16x32_bf16(alo[3][1], bh1, acc3, 0, 0, 0);
    acc0 = __builtin_amdgcn_mfma_f32_16x16x32_bf16(ahi[0][1], bl1, acc0, 0, 0, 0);
    acc1 = __builtin_amdgcn_mfma_f32_16x16x32_bf16(ahi[1][1], bl1, acc1, 0, 0, 0);
    acc2 = __builtin_amdgcn_mfma_f32_16x16x32_bf16(ahi[2][1], bl1, acc2, 0, 0, 0);
    acc3 = __builtin_amdgcn_mfma_f32_16x16x32_bf16(ahi[3][1], bl1, acc3, 0, 0, 0);

    const int code = ct * 16 + cl;
#pragma unroll
    for (int j = 0; j < 4; ++j) {
      float s0 = acc0[j] - eh, s1 = acc1[j] - eh, s2 = acc2[j] - eh, s3 = acc3[j] - eh;
      if (s0 > bsc[0][j]) { bsc[0][j] = s0; bidx[0][j] = code; }
      if (s1 > bsc[1][j]) { bsc[1][j] = s1; bidx[1][j] = code; }
      if (s2 > bsc[2][j]) { bsc[2][j] = s2; bidx[2][j] = code; }
      if (s3 > bsc[3][j]) { bsc[3][j] = s3; bidx[3][j] = code; }
    }
    bh0 = nh0; bl0 = nl0; bh1 = nh1; bl1 = nl1; eh = ehx;
  }

  // Row max over the 16 lanes (l&15) of each group; flag lane-bests within margin.
  unsigned fmask = 0;
#pragma unroll
  for (int s = 0; s < 4; ++s)
#pragma unroll
    for (int j = 0; j < 4; ++j) {
      float m = bsc[s][j];
      m = fmaxf(m, __shfl_xor(m, 1));
      m = fmaxf(m, __shfl_xor(m, 2));
      m = fmaxf(m, __shfl_xor(m, 4));
      m = fmaxf(m, __shfl_xor(m, 8));
      if (bsc[s][j] >= m - MARGIN) fmask |= 1u << (s * 4 + j);
    }

  // Exact fp32 rescore of flagged candidates (typically 1/lane), lane-compacted.
  float exact[4][4];
#pragma unroll
  for (int s = 0; s < 4; ++s)
#pragma unroll
    for (int j = 0; j < 4; ++j) exact[s][j] = -3.4e38f;

  while (__any((int)(fmask != 0))) {
    const bool act = fmask != 0;
    const int sel = __ffs(fmask) - 1;  // -1 if none (guarded by act)
    int code = 0;
#pragma unroll
    for (int s = 0; s < 4; ++s)
#pragma unroll
      for (int j = 0; j < 4; ++j)
        code = (sel == s * 4 + j) ? bidx[s][j] : code;
    int row = act ? (row0 + (sel >> 2) * 16 + grp * 4 + (sel & 3)) : row0;
    if (!act) code = 0;
    const float4* xr = (const float4*)(x + (size_t)row * DIM);
    const float4* er = (const float4*)(embed + (size_t)code * DIM);
    float a0 = 0, a1 = 0, a2 = 0, a3 = 0, n0 = 0, n1 = 0, n2 = 0, n3 = 0;
#pragma unroll
    for (int i = 0; i < 16; ++i) {
      float4 xv = xr[i], ev = er[i];
      a0 = fmaf(xv.x, ev.x, a0); a1 = fmaf(xv.y, ev.y, a1);
      a2 = fmaf(xv.z, ev.z, a2); a3 = fmaf(xv.w, ev.w, a3);
      n0 = fmaf(ev.x, ev.x, n0); n1 = fmaf(ev.y, ev.y, n1);
      n2 = fmaf(ev.z, ev.z, n2); n3 = fmaf(ev.w, ev.w, n3);
    }
    float ex = ((a0 + a1) + (a2 + a3)) - 0.5f * ((n0 + n1) + (n2 + n3));
#pragma unroll
    for (int s = 0; s < 4; ++s)
#pragma unroll
      for (int j = 0; j < 4; ++j)
        exact[s][j] = (act && sel == s * 4 + j) ? ex : exact[s][j];
    fmask = act ? (fmask & (fmask - 1)) : 0u;
  }

  // Packed (exact score, lowest-idx) reduce across the 16-lane group; combine
  // across code-split blocks via atomicMax.
#pragma unroll
  for (int s = 0; s < 4; ++s)
#pragma unroll
    for (int j = 0; j < 4; ++j) {
      unsigned long long pk = pack_score(exact[s][j], bidx[s][j]);
      unsigned long long o;
      o = __shfl_xor(pk, 1); pk = pk > o ? pk : o;
      o = __shfl_xor(pk, 2); pk = pk > o ? pk : o;
      o = __shfl_xor(pk, 4); pk = pk > o ? pk : o;
      o = __shfl_xor(pk, 8); pk = pk > o ? pk : o;
      if (cl == 0) atomicMax(&best[row0 + s * 16 + grp * 4 + j], pk);
    }
}

// Fallback (proven round-1 path) if ws is too small for the MFMA screen.
__global__ __launch_bounds__(256, 2) void vq_score_fb(
    const float* __restrict__ x, const float* __restrict__ embed,
    const float* __restrict__ enh, unsigned long long* __restrict__ best) {
  const int row = blockIdx.x * 256 + threadIdx.x;
  const int c0 = blockIdx.y * KT_FB;
  float4 xa[16];
  const float4* xg = (const float4*)(x + (size_t)row * DIM);
#pragma unroll
  for (int i = 0; i < 16; ++i) xa[i] = xg[i];
  float bs = -3.4e38f;
  int bc = 0;
#pragma unroll 2
  for (int c = c0; c < c0 + KT_FB; ++c) {
    const float4* e4 = (const float4*)(embed + (size_t)c * DIM);
    float a0 = 0.f, a1 = 0.f, a2 = 0.f, a3 = 0.f;
#pragma unroll
    for (int i = 0; i < 16; ++i) {
      float4 ev = e4[i];
      a0 = fmaf(xa[i].x, ev.x, a0); a1 = fmaf(xa[i].y, ev.y, a1);
      a2 = fmaf(xa[i].z, ev.z, a2); a3 = fmaf(xa[i].w, ev.w, a3);
    }
    float s = ((a0 + a1) + (a2 + a3)) - enh[c];
    if (s > bs) { bs = s; bc = c; }
  }
  atomicMax(&best[row], pack_score(bs, bc));
}

__global__ void vq_finalize(const unsigned long long* __restrict__ best,
                            const float* __restrict__ embed,
                            const float* __restrict__ node_mask,
                            float* __restrict__ quant,
                            float* __restrict__ out_idx,
                            float* __restrict__ counts) {
  int gid = blockIdx.x * 256 + threadIdx.x;
  int row = gid >> 6, d = gid & 63;
  unsigned long long p = best[row];
  int idx = 0xFFFF - (int)(p & 0xFFFFull);
  quant[gid] = embed[(size_t)idx * DIM + d];
  if (d == 0) {
    out_idx[row] = (float)idx;
    atomicAdd(&counts[idx], node_mask[row]);
  }
}

__global__ void vq_perplexity(const float* __restrict__ counts, float* __restrict__ out) {
  int tid = threadIdx.x;
  float acc = 0.f;
  for (int k = tid; k < NCODES; k += 256) {
    float p = counts[k] * (1.0f / (float)ROWS);
    acc += p * logf(p + 1e-10f);
  }
#pragma unroll
  for (int off = 32; off > 0; off >>= 1) acc += __shfl_down(acc, off);
  __shared__ float red[4];
  if ((tid & 63) == 0) red[tid >> 6] = acc;
  __syncthreads();
  if (tid == 0) out[0] = expf(-((red[0] + red[1]) + (red[2] + red[3])));
}

extern "C" void kernel_launch(void* const* d_in, const int* in_sizes, int n_in,
                              void* d_out, int out_size, void* d_ws, size_t ws_size,
                              hipStream_t stream) {
  const float* x = (const float*)d_in[0];
  const float* node_mask = (const float*)d_in[1];
  const float* embed = (const float*)d_in[2];

  float* out = (float*)d_out;
  float* quant = out;
  float* out_idx = out + (size_t)ROWS * DIM;
  float* out_ppl = out_idx + ROWS;

  unsigned long long* best = (unsigned long long*)((char*)d_ws + WS_BEST);
  float* counts = (float*)((char*)d_ws + WS_COUNTS);
  float* enh = (float*)((char*)d_ws + WS_ENH);
  short* eswz = (short*)((char*)d_ws + WS_ESWZ);

  hipMemsetAsync(d_ws, 0, WS_ENH, stream);  // best + counts
  vq_enorm<<<NCODES / 256, 256, 0, stream>>>(embed, enh);
  if (ws_size >= WS_NEED) {
    vq_prep_e<<<256, 256, 0, stream>>>(embed, eswz);
    vq_screen<<<dim3(ROWS / 256, NCODES / 1024), 256, 0, stream>>>(x, embed, eswz, enh, best);
  } else {
    vq_score_fb<<<dim3(ROWS / 256, NCODES / KT_FB), 256, 0, stream>>>(x, embed, enh, best);
  }
  vq_finalize<<<ROWS * DIM / 256, 256, 0, stream>>>(best, embed, node_mask, quant, out_idx, counts);
  vq_perplexity<<<1, 256, 0, stream>>>(counts, out_ppl);
}